// Round 8
// baseline (263.978 us; speedup 1.0000x reference)
//
#include <hip/hip_runtime.h>
#include <hip/hip_bf16.h>

// B=2, S=2048, D_MODEL=1024, H=16, D_HEAD=64.
// I/O fp32; mask int32 (nonzero = masked). Internals bf16 MFMA.
// R18: attn reverted to R15 exactly (best: 59.7us; R17's KVBLK=128 cost 3us).
// gemm128/gemm_out: BK=32 -> 64 (16 barrier periods instead of 32 -> halves
// exposed load-latency events; these kernels measured latency-bound with
// MfmaUtil 14%/VALU 8%/Occ 10%). 128B LDS rows would be a 16-way bank
// conflict + global_load_lds forbids padding, so: linear LDS + pre-swizzled
// global source chunk ((e&7)^(row&7)) + XOR'd read slot (both-sides swizzle,
// permutation stays inside one 128B line -> coalescing preserved).

typedef __bf16 bf16x8 __attribute__((ext_vector_type(8)));
typedef __bf16 bf16x4 __attribute__((ext_vector_type(4)));
typedef float f32x4 __attribute__((ext_vector_type(4)));

#define S_LEN 2048
#define DM 1024
#define NH 16
#define DH 64
#define MROWS 4096  // B*S

// 0.125 * log2(e): folds the 1/sqrt(DH) scale AND the exp->exp2 base change
// into the Q projection (applied in f32 before the single bf16 rounding).
#define QSCALE 0.18033688011112042f

static __device__ __forceinline__ unsigned short f2bf(float f) {
    __bf16 b = (__bf16)f;
    unsigned short u; __builtin_memcpy(&u, &b, 2); return u;
}

static __device__ __forceinline__ float exp2_hw(float x) {
#if __has_builtin(__builtin_amdgcn_exp2f)
    return __builtin_amdgcn_exp2f(x);
#else
    float r; asm("v_exp_f32 %0, %1" : "=v"(r) : "v"(x)); return r;
#endif
}

// dst.lo16 = bf16(lo), dst.hi16 = bf16(hi)  (RNE, same numerics as (__bf16))
static __device__ __forceinline__ unsigned cvtpk_bf16(float lo, float hi) {
    unsigned r;
    asm("v_cvt_pk_bf16_f32 %0, %1, %2" : "=v"(r) : "v"(lo), "v"(hi));
    return r;
}
// x'[32..63]=y[0..31]; y'[0..31]=x[32..63]
static __device__ __forceinline__ void pl32swap(unsigned &x, unsigned &y) {
    asm volatile("v_permlane32_swap_b32 %0, %1" : "+v"(x), "+v"(y));
}
// within each 32-lane half: x'[16..31]=y[0..15]; y'[0..15]=x[16..31]
static __device__ __forceinline__ void pl16swap(unsigned &x, unsigned &y) {
    asm volatile("v_permlane16_swap_b32 %0, %1" : "+v"(x), "+v"(y));
}

static __device__ __forceinline__ bf16x8 cvt8(float4 a, float4 b) {
    bf16x8 o;
    o[0] = (__bf16)a.x; o[1] = (__bf16)a.y; o[2] = (__bf16)a.z; o[3] = (__bf16)a.w;
    o[4] = (__bf16)b.x; o[5] = (__bf16)b.y; o[6] = (__bf16)b.z; o[7] = (__bf16)b.w;
    return o;
}

// Fused prep: mask bit-pack + 3 X cvts + 4 W cvts in one launch.
__global__ __launch_bounds__(256)
void prep(const int* __restrict__ m, unsigned* __restrict__ mb,
          const float* __restrict__ Q, unsigned short* __restrict__ dQ,
          const float* __restrict__ K, unsigned short* __restrict__ dK,
          const float* __restrict__ V, unsigned short* __restrict__ dV,
          const float* __restrict__ W0, unsigned short* __restrict__ dW0,
          const float* __restrict__ W1, unsigned short* __restrict__ dW1,
          const float* __restrict__ W2, unsigned short* __restrict__ dW2,
          const float* __restrict__ W3, unsigned short* __restrict__ dW3)
{
    const int bx = blockIdx.x, tid = threadIdx.x;
    if (bx < 1024) {
        const int lane = tid & 63, w = tid >> 6;
        const int row = bx * 4 + w;
        const int* src = m + (size_t)row * S_LEN;
        unsigned* dst = mb + (size_t)row * (S_LEN / 32);
        for (int i = 0; i < 32; i++) {
            int v = src[i * 64 + lane];
            unsigned long long bm = __ballot(v != 0);
            if (lane == 0) { dst[i*2] = (unsigned)bm; dst[i*2+1] = (unsigned)(bm >> 32); }
        }
    } else if (bx < 7168) {
        int t = bx - 1024;
        int which = t >> 11;
        const float* s = which == 0 ? Q : which == 1 ? K : V;
        unsigned short* d = which == 0 ? dQ : which == 1 ? dK : dV;
        int i = ((t & 2047) * 256 + tid) * 8;
        float4 a = *(const float4*)(s + i);
        float4 b = *(const float4*)(s + i + 4);
        *(bf16x8*)(d + i) = cvt8(a, b);
    } else {
        int t = bx - 7168;
        int which = t >> 9;
        const float* s = which == 0 ? W0 : which == 1 ? W1 : which == 2 ? W2 : W3;
        unsigned short* d = which == 0 ? dW0 : which == 1 ? dW1 : which == 2 ? dW2 : dW3;
        int i = ((t & 511) * 256 + tid) * 8;
        float4 a = *(const float4*)(s + i);
        float4 b = *(const float4*)(s + i + 4);
        *(bf16x8*)(d + i) = cvt8(a, b);
    }
}

// QKV GEMM: 128x128 tile, BK=64, global_load_lds with both-sides XOR swizzle.
// z: 0/1 head-split (q_ws/k_ws), 2 transposed (vt_ws). z==0 pre-scales by
// QSCALE. XCD chunk swizzle: 3MB working set per XCD L2.
__global__ __launch_bounds__(256)
void gemm128(const unsigned short* __restrict__ X0, const unsigned short* __restrict__ X1,
             const unsigned short* __restrict__ X2,
             const unsigned short* __restrict__ W0, const unsigned short* __restrict__ W1,
             const unsigned short* __restrict__ W2,
             const float* __restrict__ b0, const float* __restrict__ b1,
             const float* __restrict__ b2,
             unsigned short* __restrict__ d0, unsigned short* __restrict__ d1,
             unsigned short* __restrict__ d2)
{
    __shared__ __align__(16) unsigned short As[128 * 64];
    __shared__ __align__(16) unsigned short Bs[128 * 64];

    const int bid = blockIdx.x + blockIdx.y * 8 + blockIdx.z * 256; // 0..767
    const int xcd = bid & 7;
    const int t   = bid >> 3;
    const int z   = t >> 5;
    const int u   = t & 31;
    const int nt  = u & 7;
    const int mt  = xcd * 4 + (u >> 3);

    const unsigned short* X = z == 0 ? X0 : z == 1 ? X1 : X2;
    const unsigned short* W = z == 0 ? W0 : z == 1 ? W1 : W2;
    const float* bias        = z == 0 ? b0 : z == 1 ? b1 : b2;
    unsigned short* dstb     = z == 0 ? d0 : z == 1 ? d1 : d2;

    const int tid  = threadIdx.x;
    const int m0   = mt * 128;
    const int n0   = nt * 128;
    const int lane = tid & 63;
    const int w    = tid >> 6;
    const int wm   = (w >> 1) * 64, wn = (w & 1) * 64;
    const int lr   = lane & 15;
    const int lg   = lane >> 4;
    const int rx   = lr & 7;  // row&7 for the read-side XOR (rows ≡ lr mod 8)

    f32x4 acc[4][4];
#pragma unroll
    for (int i = 0; i < 4; i++)
#pragma unroll
        for (int j = 0; j < 4; j++) acc[i][j] = f32x4{0.f, 0.f, 0.f, 0.f};

    for (int k0 = 0; k0 < DM; k0 += 64) {
        __syncthreads();
        // Stage 128x64 per array: 4 instrs/thread each. LDS dst linear
        // (wave-uniform + lane*16); global source chunk XOR'd by row&7.
#pragma unroll
        for (int j = 0; j < 4; j++) {
            int e = tid + j * 256;
            int row = e >> 3;
            int c8 = ((e & 7) ^ (row & 7)) * 8;
            __builtin_amdgcn_global_load_lds(
                (const __attribute__((address_space(1))) unsigned*)&X[(size_t)(m0 + row) * DM + k0 + c8],
                (__attribute__((address_space(3))) unsigned*)&As[e * 8], 16, 0, 0);
            __builtin_amdgcn_global_load_lds(
                (const __attribute__((address_space(1))) unsigned*)&W[(size_t)(n0 + row) * DM + k0 + c8],
                (__attribute__((address_space(3))) unsigned*)&Bs[e * 8], 16, 0, 0);
        }
        __syncthreads();
        // Two K=32 halves from the same staged tile.
#pragma unroll
        for (int hh = 0; hh < 2; hh++) {
            bf16x8 af[4], bfr[4];
#pragma unroll
            for (int mi = 0; mi < 4; mi++) {
                int slot = (hh * 4 + lg) ^ rx;
                af[mi] = *(const bf16x8*)(&As[(wm + mi * 16 + lr) * 64 + slot * 8]);
            }
#pragma unroll
            for (int ni = 0; ni < 4; ni++) {
                int slot = (hh * 4 + lg) ^ rx;
                bfr[ni] = *(const bf16x8*)(&Bs[(wn + ni * 16 + lr) * 64 + slot * 8]);
            }
#pragma unroll
            for (int mi = 0; mi < 4; mi++)
#pragma unroll
                for (int ni = 0; ni < 4; ni++)
                    acc[mi][ni] = __builtin_amdgcn_mfma_f32_16x16x32_bf16(
                        af[mi], bfr[ni], acc[mi][ni], 0, 0, 0);
        }
    }

    // C/D layout: col = lane&15 -> n, row = (lane>>4)*4 + reg -> m.
#pragma unroll
    for (int mi = 0; mi < 4; mi++) {
#pragma unroll
        for (int ni = 0; ni < 4; ni++) {
            const int gcol = n0 + wn + ni * 16 + lr;
            const float bv = bias[gcol];
            const int grow0 = m0 + wm + mi * 16 + lg * 4;
            if (z == 2) {
                int b = grow0 >> 11, s = grow0 & (S_LEN - 1);
                int h = gcol >> 6, dh = gcol & 63;
                bf16x4 pk;
#pragma unroll
                for (int r = 0; r < 4; r++) pk[r] = (__bf16)(acc[mi][ni][r] + bv);
                size_t di = ((size_t)(b * NH + h) * DH + dh) * S_LEN + s;
                *(bf16x4*)(&dstb[di]) = pk;
            } else {
#pragma unroll
                for (int r = 0; r < 4; r++) {
                    int grow = grow0 + r;
                    float v = acc[mi][ni][r] + bv;
                    if (z == 0) v *= QSCALE;
                    int b = grow >> 11, s = grow & (S_LEN - 1);
                    int h = gcol >> 6, dh = gcol & 63;
                    dstb[((size_t)(b * NH + h) * S_LEN + s) * DH + dh] = f2bf(v);
                }
            }
        }
    }
}

// Out-projection: Y = X @ Wo^T + bo, fp32 out. 128M x 64N tiles, 512 blocks,
// BK=64 with both-sides XOR swizzle, XCD chunk swizzle.
__global__ __launch_bounds__(256, 4)
void gemm_out(const unsigned short* __restrict__ X, const unsigned short* __restrict__ W,
              const float* __restrict__ bias, float* __restrict__ dst)
{
    __shared__ __align__(16) unsigned short As[128 * 64];
    __shared__ __align__(16) unsigned short Bs[64 * 64];

    const int bid = blockIdx.x + blockIdx.y * 16; // 0..511
    const int xcd = bid & 7;
    const int u   = bid >> 3;
    const int nt  = u & 15;
    const int mt  = xcd * 4 + (u >> 4);

    const int tid  = threadIdx.x;
    const int m0   = mt * 128;
    const int n0   = nt * 64;
    const int lane = tid & 63;
    const int w    = tid >> 6;
    const int wm   = (w >> 1) * 64, wn = (w & 1) * 32;
    const int lr   = lane & 15;
    const int lg   = lane >> 4;
    const int rx   = lr & 7;

    f32x4 acc[4][2];
#pragma unroll
    for (int i = 0; i < 4; i++)
#pragma unroll
        for (int j = 0; j < 2; j++) acc[i][j] = f32x4{0.f, 0.f, 0.f, 0.f};

    for (int k0 = 0; k0 < DM; k0 += 64) {
        __syncthreads();
#pragma unroll
        for (int j = 0; j < 4; j++) {
            int e = tid + j * 256;
            int row = e >> 3;
            int c8 = ((e & 7) ^ (row & 7)) * 8;
            __builtin_amdgcn_global_load_lds(
                (const __attribute__((address_space(1))) unsigned*)&X[(size_t)(m0 + row) * DM + k0 + c8],
                (__attribute__((address_space(3))) unsigned*)&As[e * 8], 16, 0, 0);
        }
#pragma unroll
        for (int j = 0; j < 2; j++) {
            int e = tid + j * 256;
            int row = e >> 3;
            int c8 = ((e & 7) ^ (row & 7)) * 8;
            __builtin_amdgcn_global_load_lds(
                (const __attribute__((address_space(1))) unsigned*)&W[(size_t)(n0 + row) * DM + k0 + c8],
                (__attribute__((address_space(3))) unsigned*)&Bs[e * 8], 16, 0, 0);
        }
        __syncthreads();
#pragma unroll
        for (int hh = 0; hh < 2; hh++) {
            bf16x8 af[4], bfr[2];
            int slot = (hh * 4 + lg) ^ rx;
#pragma unroll
            for (int mi = 0; mi < 4; mi++)
                af[mi] = *(const bf16x8*)(&As[(wm + mi * 16 + lr) * 64 + slot * 8]);
#pragma unroll
            for (int ni = 0; ni < 2; ni++)
                bfr[ni] = *(const bf16x8*)(&Bs[(wn + ni * 16 + lr) * 64 + slot * 8]);
#pragma unroll
            for (int mi = 0; mi < 4; mi++)
#pragma unroll
                for (int ni = 0; ni < 2; ni++)
                    acc[mi][ni] = __builtin_amdgcn_mfma_f32_16x16x32_bf16(
                        af[mi], bfr[ni], acc[mi][ni], 0, 0, 0);
        }
    }
#pragma unroll
    for (int mi = 0; mi < 4; mi++)
#pragma unroll
        for (int ni = 0; ni < 2; ni++) {
            const int gcol = n0 + wn + ni * 16 + lr;
            const float bv = bias[gcol];
            const int grow0 = m0 + wm + mi * 16 + lg * 4;
#pragma unroll
            for (int r = 0; r < 4; r++)
                dst[(size_t)(grow0 + r) * DM + gcol] = acc[mi][ni][r] + bv;
        }
}

// Flash attention (transposed): S^T = K*Q^T, softmax rows along lanes.
// Wave owns 2 q-tiles (32 q). K/V LDS double-buffer (1 barrier/iter).
// P^T built in-register (cvt_pk + permlane butterfly) -> no Pq LDS.
// Row-sum via ones-MFMA. Grid 512 (XCD swizzle), 4 waves, 2 blocks/CU.
// (R15 config verbatim — best measured: 59.7us.)
__global__ __launch_bounds__(256, 2)
void attn(const unsigned short* __restrict__ q_ws,
          const unsigned short* __restrict__ k_ws,
          const unsigned short* __restrict__ vt_ws,
          const unsigned* __restrict__ mbits,
          unsigned short* __restrict__ ctx)
{
    __shared__ __align__(16) unsigned short Ks[2][64 * 72];   // [kv][dh], +8 pad
    __shared__ __align__(16) unsigned short Vs[2][64 * 72];   // [dh][kv], +8 pad
    const int tid = threadIdx.x, lane = tid & 63, w = tid >> 6;
    const int lr = lane & 15, lg = lane >> 4;

    const int i    = blockIdx.x;            // 0..511
    const int xcd  = i & 7;
    const int slot = i >> 3;                // 0..63
    const int bh   = xcd * 4 + (slot >> 4); // 4 bh per XCD (K/V L2-resident)
    const int qblk = slot & 15;
    const int b  = bh >> 4;
    const int h  = bh & 15;
    const int q0 = qblk * 128 + w * 32;
    const int qA = q0 + lr;
    const int qB = q0 + 16 + lr;

    const int srow = tid >> 3;   // staging row
    const int sseg = tid & 7;    // 16B segment

    const unsigned short* qh = q_ws + (size_t)bh * S_LEN * DH;
    const unsigned short* kh = k_ws + (size_t)bh * S_LEN * DH;
    const unsigned short* vh = vt_ws + (size_t)bh * DH * S_LEN;
    const unsigned* mrA = mbits + (size_t)(b * S_LEN + qA) * (S_LEN / 32);
    const unsigned* mrB = mbits + (size_t)(b * S_LEN + qB) * (S_LEN / 32);

    // Q fragments (B operand of K*Q^T): Q[q][dh = c*32 + lg*8 + j].
    bf16x8 aqA[2], aqB[2];
#pragma unroll
    for (int c = 0; c < 2; c++) {
        aqA[c] = *(const bf16x8*)(&qh[(size_t)qA * DH + c * 32 + lg * 8]);
        aqB[c] = *(const bf16x8*)(&qh[(size_t)qB * DH + c * 32 + lg * 8]);
    }

    bf16x8 ones;
#pragma unroll
    for (int j = 0; j < 8; j++) ones[j] = (__bf16)1.0f;

    f32x4 accA[4], accB[4], accRA, accRB;
#pragma unroll
    for (int di = 0; di < 4; di++) {
        accA[di] = f32x4{0.f, 0.f, 0.f, 0.f};
        accB[di] = f32x4{0.f, 0.f, 0.f, 0.f};
    }
    accRA = f32x4{0.f, 0.f, 0.f, 0.f};
    accRB = f32x4{0.f, 0.f, 0.f, 0.f};

    // Prologue: tile 0 -> Ks[0]/Vs[0]; tile 1 -> staging regs.
    uint4 kreg0, kreg1, vreg0, vreg1;
    kreg0 = *(const uint4*)(&kh[(size_t)(srow)      * DH + sseg * 8]);
    kreg1 = *(const uint4*)(&kh[(size_t)(srow + 32) * DH + sseg * 8]);
    vreg0 = *(const uint4*)(&vh[(size_t)(srow)      * S_LEN + sseg * 8]);
    vreg1 = *(const uint4*)(&vh[(size_t)(srow + 32) * S_LEN + sseg * 8]);
    *(uint4*)(&Ks[0][(srow)      * 72 + sseg * 8]) = kreg0;
    *(uint4*)(&Ks[0][(srow + 32) * 72 + sseg * 8]) = kreg1;
    *(uint4*)(&Vs[0][(srow)      * 72 + sseg * 8]) = vreg0;
    *(uint4*)(&Vs[0][(srow + 32) * 72 + sseg * 8]) = vreg1;
    kreg0 = *(const uint4*)(&kh[(size_t)(64 + srow)      * DH + sseg * 8]);
    kreg1 = *(const uint4*)(&kh[(size_t)(64 + srow + 32) * DH + sseg * 8]);
    vreg0 = *(const uint4*)(&vh[(size_t)(srow)      * S_LEN + 64 + sseg * 8]);
    vreg1 = *(const uint4*)(&vh[(size_t)(srow + 32) * S_LEN + 64 + sseg * 8]);
    __syncthreads();

    for (int it = 0; it < 32; it++) {
        const int cur = it & 1;
        const unsigned short* Kc = &Ks[cur][0];
        const unsigned short* Vc = &Vs[cur][0];
        if (it < 31) {
            unsigned short* Kn = &Ks[cur ^ 1][0];
            unsigned short* Vn = &Vs[cur ^ 1][0];
            *(uint4*)(&Kn[(srow)      * 72 + sseg * 8]) = kreg0;
            *(uint4*)(&Kn[(srow + 32) * 72 + sseg * 8]) = kreg1;
            *(uint4*)(&Vn[(srow)      * 72 + sseg * 8]) = vreg0;
            *(uint4*)(&Vn[(srow + 32) * 72 + sseg * 8]) = vreg1;
        }
        if (it < 30) {
            const int kn = (it + 2) * 64;
            kreg0 = *(const uint4*)(&kh[(size_t)(kn + srow)      * DH + sseg * 8]);
            kreg1 = *(const uint4*)(&kh[(size_t)(kn + srow + 32) * DH + sseg * 8]);
            vreg0 = *(const uint4*)(&vh[(size_t)(srow)      * S_LEN + kn + sseg * 8]);
            vreg1 = *(const uint4*)(&vh[(size_t)(srow + 32) * S_LEN + kn + sseg * 8]);
        }

        const uint2 mwA = *(const uint2*)(&mrA[it * 2]);
        const uint2 mwB = *(const uint2*)(&mrB[it * 2]);

        // S^T tiles: D[row=kv_loc=lg*4+r][col=q=lr], kv = it*64+ni*16+lg*4+r.
        f32x4 sA[4], sB[4];
        __builtin_amdgcn_s_setprio(1);
#pragma unroll
        for (int ni = 0; ni < 4; ni++) {
            bf16x8 ak0 = *(const bf16x8*)(&Kc[(ni * 16 + lr) * 72 + lg * 8]);
            bf16x8 ak1 = *(const bf16x8*)(&Kc[(ni * 16 + lr) * 72 + 32 + lg * 8]);
            f32x4 tA = __builtin_amdgcn_mfma_f32_16x16x32_bf16(ak0, aqA[0], f32x4{0.f,0.f,0.f,0.f}, 0,0,0);
            tA = __builtin_amdgcn_mfma_f32_16x16x32_bf16(ak1, aqA[1], tA, 0,0,0);
            f32x4 tB = __builtin_amdgcn_mfma_f32_16x16x32_bf16(ak0, aqB[0], f32x4{0.f,0.f,0.f,0.f}, 0,0,0);
            tB = __builtin_amdgcn_mfma_f32_16x16x32_bf16(ak1, aqB[1], tB, 0,0,0);
            sA[ni] = tA; sB[ni] = tB;
        }
        __builtin_amdgcn_s_setprio(0);

        // Softmax numerator: p = masked ? 0 : exp2(s)  (s pre-scaled in Q).
#pragma unroll
        for (int ni = 0; ni < 4; ni++) {
            unsigned wA = (ni & 2) ? mwA.y : mwA.x;
            unsigned wB = (ni & 2) ? mwB.y : mwB.x;
            unsigned nibA = wA >> ((ni & 1) * 16 + lg * 4);
            unsigned nibB = wB >> ((ni & 1) * 16 + lg * 4);
#pragma unroll
            for (int r = 0; r < 4; r++) {
                float pA = exp2_hw(sA[ni][r]);
                float pB = exp2_hw(sB[ni][r]);
                sA[ni][r] = (nibA & (1u << r)) ? 0.f : pA;
                sB[ni][r] = (nibB & (1u << r)) ? 0.f : pB;
            }
        }

        // In-register P^T: lane (lr,lg) holds P[q=lr][kv=16ni+4lg+r].
        // Pack r-pairs then 2-stage permlane butterfly -> lane (lr,g) holds
        // P[q=lr][kv = 32c + 8g + j], j=0..7 (verified in R14).
        unsigned wpA[8], wpB[8];
#pragma unroll
        for (int ni = 0; ni < 4; ni++) {
            wpA[ni*2]   = cvtpk_bf16(sA[ni][0], sA[ni][1]);
            wpA[ni*2+1] = cvtpk_bf16(sA[ni][2], sA[ni][3]);
            wpB[ni*2]   = cvtpk_bf16(sB[ni][0], sB[ni][1]);
            wpB[ni*2+1] = cvtpk_bf16(sB[ni][2], sB[ni][3]);
        }
#pragma unroll
        for (int c = 0; c < 2; c++) {
            pl32swap(wpA[c*4 + 0], wpA[c*4 + 2]);
            pl32swap(wpA[c*4 + 1], wpA[c*4 + 3]);
            pl16swap(wpA[c*4 + 0], wpA[c*4 + 2]);
            pl16swap(wpA[c*4 + 1], wpA[c*4 + 3]);
            pl32swap(wpB[c*4 + 0], wpB[c*4 + 2]);
            pl32swap(wpB[c*4 + 1], wpB[c*4 + 3]);
            pl16swap(wpB[c*4 + 0], wpB[c*4 + 2]);
            pl16swap(wpB[c*4 + 1], wpB[c*4 + 3]);
        }
        bf16x8 bpA0, bpA1, bpB0, bpB1;
        __builtin_memcpy(&bpA0, &wpA[0], 16);
        __builtin_memcpy(&bpA1, &wpA[4], 16);
        __builtin_memcpy(&bpB0, &wpB[0], 16);
        __builtin_memcpy(&bpB1, &wpB[4], 16);

        // O^T += V^T * P^T; row sums on the matrix pipe.
        __builtin_amdgcn_s_setprio(1);
#pragma unroll
        for (int di = 0; di < 4; di++) {
            bf16x8 av0 = *(const bf16x8*)(&Vc[(di * 16 + lr) * 72 + lg * 8]);
            bf16x8 av1 = *(const bf16x8*)(&Vc[(di * 16 + lr) * 72 + 32 + lg * 8]);
            accA[di] = __builtin_amdgcn_mfma_f32_16x16x32_bf16(av0, bpA0, accA[di], 0, 0, 0);
            accA[di] = __builtin_amdgcn_mfma_f32_16x16x32_bf16(av1, bpA1, accA[di], 0, 0, 0);
            accB[di] = __builtin_amdgcn_mfma_f32_16x16x32_bf16(av0, bpB0, accB[di], 0, 0, 0);
            accB[di] = __builtin_amdgcn_mfma_f32_16x16x32_bf16(av1, bpB1, accB[di], 0, 0, 0);
        }
        accRA = __builtin_amdgcn_mfma_f32_16x16x32_bf16(ones, bpA0, accRA, 0, 0, 0);
        accRA = __builtin_amdgcn_mfma_f32_16x16x32_bf16(ones, bpA1, accRA, 0, 0, 0);
        accRB = __builtin_amdgcn_mfma_f32_16x16x32_bf16(ones, bpB0, accRB, 0, 0, 0);
        accRB = __builtin_amdgcn_mfma_f32_16x16x32_bf16(ones, bpB1, accRB, 0, 0, 0);
        __builtin_amdgcn_s_setprio(0);

        __syncthreads();
    }

    const float invA = 1.0f / fmaxf(accRA[0], 1e-37f);
    const float invB = 1.0f / fmaxf(accRB[0], 1e-37f);

    unsigned short* crowA = &ctx[((size_t)(b * S_LEN + qA)) * DM + h * DH];
    unsigned short* crowB = &ctx[((size_t)(b * S_LEN + qB)) * DM + h * DH];
#pragma unroll
    for (int di = 0; di < 4; di++) {
        bf16x4 oA, oB;
#pragma unroll
        for (int r = 0; r < 4; r++) {
            oA[r] = (__bf16)(accA[di][r] * invA);
            oB[r] = (__bf16)(accB[di][r] * invB);
        }
        *(bf16x4*)(&crowA[di * 16 + lg * 4]) = oA;
        *(bf16x4*)(&crowB[di * 16 + lg * 4]) = oB;
    }
}

extern "C" void kernel_launch(void* const* d_in, const int* in_sizes, int n_in,
                              void* d_out, int out_size, void* d_ws, size_t ws_size,
                              hipStream_t stream)
{
    (void)in_sizes; (void)n_in; (void)out_size; (void)ws_size;
    const float* Q  = (const float*)d_in[0];
    const float* K  = (const float*)d_in[1];
    const float* V  = (const float*)d_in[2];
    const int*   Mk = (const int*)d_in[3];
    const float* Wq = (const float*)d_in[4];
    const float* bq = (const float*)d_in[5];
    const float* Wk = (const float*)d_in[6];
    const float* bk = (const float*)d_in[7];
    const float* Wv = (const float*)d_in[8];
    const float* bv = (const float*)d_in[9];
    const float* Wo = (const float*)d_in[10];
    const float* bo = (const float*)d_in[11];

    const int NX = MROWS * DM;   // 4194304
    const int NW = DM * DM;      // 1048576

    unsigned short* q_ws  = (unsigned short*)d_ws;
    unsigned short* k_ws  = q_ws + (size_t)NX;
    unsigned short* vt_ws = k_ws + (size_t)NX;
    unsigned short* ctx   = vt_ws + (size_t)NX;
    unsigned*       mbits = (unsigned*)(ctx + (size_t)NX);
    unsigned short* Wbq   = (unsigned short*)(mbits + (size_t)MROWS * (S_LEN / 32));
    unsigned short* Wbk   = Wbq + (size_t)NW;
    unsigned short* Wbv   = Wbk + (size_t)NW;
    unsigned short* Wbo   = Wbv + (size_t)NW;
    unsigned short* Xbq   = Wbo + (size_t)NW;
    unsigned short* Xbk   = Xbq + (size_t)NX;
    unsigned short* Xbv   = Xbk + (size_t)NX;
    float* out = (float*)d_out;

    dim3 blk(256);
    prep<<<dim3(9216), blk, 0, stream>>>(Mk, mbits, Q, Xbq, K, Xbk, V, Xbv,
                                         Wq, Wbq, Wk, Wbk, Wv, Wbv, Wo, Wbo);

    gemm128<<<dim3(8, 32, 3), blk, 0, stream>>>(Xbq, Xbk, Xbv, Wbq, Wbk, Wbv,
                                                bq, bk, bv, q_ws, k_ws, vt_ws);

    attn<<<dim3(512), blk, 0, stream>>>(q_ws, k_ws, vt_ws, mbits, ctx);

    gemm_out<<<dim3(16, 32), blk, 0, stream>>>(ctx, Wbo, bo, out);
}

// Round 9
// 258.800 us; speedup vs baseline: 1.0200x; 1.0200x over previous
//
#include <hip/hip_runtime.h>
#include <hip/hip_bf16.h>

// B=2, S=2048, D_MODEL=1024, H=16, D_HEAD=64.
// I/O fp32; mask int32 (nonzero = masked). Internals bf16 MFMA.
// R19: measured-best composition. gemms = R13/R17 form (BK=32, XCD chunk
// swizzle, single-buffer; R18's BK=64+swizzle zeroed bank conflicts and cut
// FETCH 101->37MB but regressed dur — conflicts/fetch weren't the critical
// path). attn = R15 form verbatim (59.7us best: K/V dbuf 1-barrier/iter +
// in-register P^T via cvt_pk + permlane32/16 butterfly).

typedef __bf16 bf16x8 __attribute__((ext_vector_type(8)));
typedef __bf16 bf16x4 __attribute__((ext_vector_type(4)));
typedef float f32x4 __attribute__((ext_vector_type(4)));

#define S_LEN 2048
#define DM 1024
#define NH 16
#define DH 64
#define MROWS 4096  // B*S

// 0.125 * log2(e): folds the 1/sqrt(DH) scale AND the exp->exp2 base change
// into the Q projection (applied in f32 before the single bf16 rounding).
#define QSCALE 0.18033688011112042f

static __device__ __forceinline__ unsigned short f2bf(float f) {
    __bf16 b = (__bf16)f;
    unsigned short u; __builtin_memcpy(&u, &b, 2); return u;
}

static __device__ __forceinline__ float exp2_hw(float x) {
#if __has_builtin(__builtin_amdgcn_exp2f)
    return __builtin_amdgcn_exp2f(x);
#else
    float r; asm("v_exp_f32 %0, %1" : "=v"(r) : "v"(x)); return r;
#endif
}

// dst.lo16 = bf16(lo), dst.hi16 = bf16(hi)  (RNE, same numerics as (__bf16))
static __device__ __forceinline__ unsigned cvtpk_bf16(float lo, float hi) {
    unsigned r;
    asm("v_cvt_pk_bf16_f32 %0, %1, %2" : "=v"(r) : "v"(lo), "v"(hi));
    return r;
}
// x'[32..63]=y[0..31]; y'[0..31]=x[32..63]
static __device__ __forceinline__ void pl32swap(unsigned &x, unsigned &y) {
    asm volatile("v_permlane32_swap_b32 %0, %1" : "+v"(x), "+v"(y));
}
// within each 32-lane half: x'[16..31]=y[0..15]; y'[0..15]=x[16..31]
static __device__ __forceinline__ void pl16swap(unsigned &x, unsigned &y) {
    asm volatile("v_permlane16_swap_b32 %0, %1" : "+v"(x), "+v"(y));
}

static __device__ __forceinline__ bf16x8 cvt8(float4 a, float4 b) {
    bf16x8 o;
    o[0] = (__bf16)a.x; o[1] = (__bf16)a.y; o[2] = (__bf16)a.z; o[3] = (__bf16)a.w;
    o[4] = (__bf16)b.x; o[5] = (__bf16)b.y; o[6] = (__bf16)b.z; o[7] = (__bf16)b.w;
    return o;
}

// Fused prep: mask bit-pack + 3 X cvts + 4 W cvts in one launch.
__global__ __launch_bounds__(256)
void prep(const int* __restrict__ m, unsigned* __restrict__ mb,
          const float* __restrict__ Q, unsigned short* __restrict__ dQ,
          const float* __restrict__ K, unsigned short* __restrict__ dK,
          const float* __restrict__ V, unsigned short* __restrict__ dV,
          const float* __restrict__ W0, unsigned short* __restrict__ dW0,
          const float* __restrict__ W1, unsigned short* __restrict__ dW1,
          const float* __restrict__ W2, unsigned short* __restrict__ dW2,
          const float* __restrict__ W3, unsigned short* __restrict__ dW3)
{
    const int bx = blockIdx.x, tid = threadIdx.x;
    if (bx < 1024) {
        const int lane = tid & 63, w = tid >> 6;
        const int row = bx * 4 + w;
        const int* src = m + (size_t)row * S_LEN;
        unsigned* dst = mb + (size_t)row * (S_LEN / 32);
        for (int i = 0; i < 32; i++) {
            int v = src[i * 64 + lane];
            unsigned long long bm = __ballot(v != 0);
            if (lane == 0) { dst[i*2] = (unsigned)bm; dst[i*2+1] = (unsigned)(bm >> 32); }
        }
    } else if (bx < 7168) {
        int t = bx - 1024;
        int which = t >> 11;
        const float* s = which == 0 ? Q : which == 1 ? K : V;
        unsigned short* d = which == 0 ? dQ : which == 1 ? dK : dV;
        int i = ((t & 2047) * 256 + tid) * 8;
        float4 a = *(const float4*)(s + i);
        float4 b = *(const float4*)(s + i + 4);
        *(bf16x8*)(d + i) = cvt8(a, b);
    } else {
        int t = bx - 7168;
        int which = t >> 9;
        const float* s = which == 0 ? W0 : which == 1 ? W1 : which == 2 ? W2 : W3;
        unsigned short* d = which == 0 ? dW0 : which == 1 ? dW1 : which == 2 ? dW2 : dW3;
        int i = ((t & 511) * 256 + tid) * 8;
        float4 a = *(const float4*)(s + i);
        float4 b = *(const float4*)(s + i + 4);
        *(bf16x8*)(d + i) = cvt8(a, b);
    }
}

// m97-style GEMM for QKV: 128x128 tile, BK=32, global_load_lds. z = mode:
// 0/1: head-split bf16 (q_ws/k_ws); 2: transposed bf16 (vt_ws).
// z==0 (Q) epilogue pre-scales by QSCALE. XCD chunk swizzle: each XCD owns
// (all 8 n-tiles x 4 m-tiles) per z -> 3MB working set per XCD L2.
__global__ __launch_bounds__(256)
void gemm128(const unsigned short* __restrict__ X0, const unsigned short* __restrict__ X1,
             const unsigned short* __restrict__ X2,
             const unsigned short* __restrict__ W0, const unsigned short* __restrict__ W1,
             const unsigned short* __restrict__ W2,
             const float* __restrict__ b0, const float* __restrict__ b1,
             const float* __restrict__ b2,
             unsigned short* __restrict__ d0, unsigned short* __restrict__ d1,
             unsigned short* __restrict__ d2)
{
    __shared__ __align__(16) unsigned short As[128 * 32];
    __shared__ __align__(16) unsigned short Bs[128 * 32];

    const int bid = blockIdx.x + blockIdx.y * 8 + blockIdx.z * 256; // 0..767
    const int xcd = bid & 7;
    const int t   = bid >> 3;
    const int z   = t >> 5;
    const int u   = t & 31;
    const int nt  = u & 7;
    const int mt  = xcd * 4 + (u >> 3);

    const unsigned short* X = z == 0 ? X0 : z == 1 ? X1 : X2;
    const unsigned short* W = z == 0 ? W0 : z == 1 ? W1 : W2;
    const float* bias        = z == 0 ? b0 : z == 1 ? b1 : b2;
    unsigned short* dstb     = z == 0 ? d0 : z == 1 ? d1 : d2;

    const int tid  = threadIdx.x;
    const int m0   = mt * 128;
    const int n0   = nt * 128;
    const int lane = tid & 63;
    const int w    = tid >> 6;
    const int wm   = (w >> 1) * 64, wn = (w & 1) * 64;
    const int lr   = lane & 15;
    const int lg   = lane >> 4;

    f32x4 acc[4][4];
#pragma unroll
    for (int i = 0; i < 4; i++)
#pragma unroll
        for (int j = 0; j < 4; j++) acc[i][j] = f32x4{0.f, 0.f, 0.f, 0.f};

    for (int k0 = 0; k0 < DM; k0 += 32) {
        __syncthreads();
#pragma unroll
        for (int j = 0; j < 2; j++) {
            int e = tid + j * 256;
            int row = e >> 2, c8 = (e & 3) * 8;
            __builtin_amdgcn_global_load_lds(
                (const __attribute__((address_space(1))) unsigned*)&X[(size_t)(m0 + row) * DM + k0 + c8],
                (__attribute__((address_space(3))) unsigned*)&As[e * 8], 16, 0, 0);
            __builtin_amdgcn_global_load_lds(
                (const __attribute__((address_space(1))) unsigned*)&W[(size_t)(n0 + row) * DM + k0 + c8],
                (__attribute__((address_space(3))) unsigned*)&Bs[e * 8], 16, 0, 0);
        }
        __syncthreads();
        bf16x8 af[4], bfr[4];
#pragma unroll
        for (int mi = 0; mi < 4; mi++)
            af[mi] = *(const bf16x8*)(&As[(wm + mi * 16 + lr) * 32 + lg * 8]);
#pragma unroll
        for (int ni = 0; ni < 4; ni++)
            bfr[ni] = *(const bf16x8*)(&Bs[(wn + ni * 16 + lr) * 32 + lg * 8]);
#pragma unroll
        for (int mi = 0; mi < 4; mi++)
#pragma unroll
            for (int ni = 0; ni < 4; ni++)
                acc[mi][ni] = __builtin_amdgcn_mfma_f32_16x16x32_bf16(
                    af[mi], bfr[ni], acc[mi][ni], 0, 0, 0);
    }

    // C/D layout: col = lane&15 -> n, row = (lane>>4)*4 + reg -> m.
#pragma unroll
    for (int mi = 0; mi < 4; mi++) {
#pragma unroll
        for (int ni = 0; ni < 4; ni++) {
            const int gcol = n0 + wn + ni * 16 + lr;
            const float bv = bias[gcol];
            const int grow0 = m0 + wm + mi * 16 + lg * 4;
            if (z == 2) {
                int b = grow0 >> 11, s = grow0 & (S_LEN - 1);
                int h = gcol >> 6, dh = gcol & 63;
                bf16x4 pk;
#pragma unroll
                for (int r = 0; r < 4; r++) pk[r] = (__bf16)(acc[mi][ni][r] + bv);
                size_t di = ((size_t)(b * NH + h) * DH + dh) * S_LEN + s;
                *(bf16x4*)(&dstb[di]) = pk;
            } else {
#pragma unroll
                for (int r = 0; r < 4; r++) {
                    int grow = grow0 + r;
                    float v = acc[mi][ni][r] + bv;
                    if (z == 0) v *= QSCALE;
                    int b = grow >> 11, s = grow & (S_LEN - 1);
                    int h = gcol >> 6, dh = gcol & 63;
                    dstb[((size_t)(b * NH + h) * S_LEN + s) * DH + dh] = f2bf(v);
                }
            }
        }
    }
}

// Out-projection: Y = X @ Wo^T + bo, fp32 out. 128M x 64N tiles, 512 blocks,
// XCD chunk swizzle (16 n-tiles x 4 m-tiles/XCD).
__global__ __launch_bounds__(256, 4)
void gemm_out(const unsigned short* __restrict__ X, const unsigned short* __restrict__ W,
              const float* __restrict__ bias, float* __restrict__ dst)
{
    __shared__ __align__(16) unsigned short As[128 * 32];
    __shared__ __align__(16) unsigned short Bs[64 * 32];

    const int bid = blockIdx.x + blockIdx.y * 16; // 0..511
    const int xcd = bid & 7;
    const int u   = bid >> 3;
    const int nt  = u & 15;
    const int mt  = xcd * 4 + (u >> 4);

    const int tid  = threadIdx.x;
    const int m0   = mt * 128;
    const int n0   = nt * 64;
    const int lane = tid & 63;
    const int w    = tid >> 6;
    const int wm   = (w >> 1) * 64, wn = (w & 1) * 32;
    const int lr   = lane & 15;
    const int lg   = lane >> 4;

    f32x4 acc[4][2];
#pragma unroll
    for (int i = 0; i < 4; i++)
#pragma unroll
        for (int j = 0; j < 2; j++) acc[i][j] = f32x4{0.f, 0.f, 0.f, 0.f};

    for (int k0 = 0; k0 < DM; k0 += 32) {
        __syncthreads();
#pragma unroll
        for (int j = 0; j < 2; j++) {
            int e = tid + j * 256;
            int row = e >> 2, c8 = (e & 3) * 8;
            __builtin_amdgcn_global_load_lds(
                (const __attribute__((address_space(1))) unsigned*)&X[(size_t)(m0 + row) * DM + k0 + c8],
                (__attribute__((address_space(3))) unsigned*)&As[e * 8], 16, 0, 0);
        }
        {
            int row = tid >> 2, c8 = (tid & 3) * 8;
            __builtin_amdgcn_global_load_lds(
                (const __attribute__((address_space(1))) unsigned*)&W[(size_t)(n0 + row) * DM + k0 + c8],
                (__attribute__((address_space(3))) unsigned*)&Bs[tid * 8], 16, 0, 0);
        }
        __syncthreads();
        bf16x8 af[4], bfr[2];
#pragma unroll
        for (int mi = 0; mi < 4; mi++)
            af[mi] = *(const bf16x8*)(&As[(wm + mi * 16 + lr) * 32 + lg * 8]);
#pragma unroll
        for (int ni = 0; ni < 2; ni++)
            bfr[ni] = *(const bf16x8*)(&Bs[(wn + ni * 16 + lr) * 32 + lg * 8]);
#pragma unroll
        for (int mi = 0; mi < 4; mi++)
#pragma unroll
            for (int ni = 0; ni < 2; ni++)
                acc[mi][ni] = __builtin_amdgcn_mfma_f32_16x16x32_bf16(
                    af[mi], bfr[ni], acc[mi][ni], 0, 0, 0);
    }
#pragma unroll
    for (int mi = 0; mi < 4; mi++)
#pragma unroll
        for (int ni = 0; ni < 2; ni++) {
            const int gcol = n0 + wn + ni * 16 + lr;
            const float bv = bias[gcol];
            const int grow0 = m0 + wm + mi * 16 + lg * 4;
#pragma unroll
            for (int r = 0; r < 4; r++)
                dst[(size_t)(grow0 + r) * DM + gcol] = acc[mi][ni][r] + bv;
        }
}

// Flash attention (transposed): S^T = K*Q^T, softmax rows along lanes.
// Wave owns 2 q-tiles (32 q). K/V LDS double-buffer (1 barrier/iter).
// P^T built in-register (cvt_pk + permlane butterfly) -> no Pq LDS.
// Row-sum via ones-MFMA. Grid 512 (XCD swizzle), 4 waves, 2 blocks/CU.
// (R15 config verbatim — best measured: 59.7us.)
__global__ __launch_bounds__(256, 2)
void attn(const unsigned short* __restrict__ q_ws,
          const unsigned short* __restrict__ k_ws,
          const unsigned short* __restrict__ vt_ws,
          const unsigned* __restrict__ mbits,
          unsigned short* __restrict__ ctx)
{
    __shared__ __align__(16) unsigned short Ks[2][64 * 72];   // [kv][dh], +8 pad
    __shared__ __align__(16) unsigned short Vs[2][64 * 72];   // [dh][kv], +8 pad
    const int tid = threadIdx.x, lane = tid & 63, w = tid >> 6;
    const int lr = lane & 15, lg = lane >> 4;

    const int i    = blockIdx.x;            // 0..511
    const int xcd  = i & 7;
    const int slot = i >> 3;                // 0..63
    const int bh   = xcd * 4 + (slot >> 4); // 4 bh per XCD (K/V L2-resident)
    const int qblk = slot & 15;
    const int b  = bh >> 4;
    const int h  = bh & 15;
    const int q0 = qblk * 128 + w * 32;
    const int qA = q0 + lr;
    const int qB = q0 + 16 + lr;

    const int srow = tid >> 3;   // staging row
    const int sseg = tid & 7;    // 16B segment

    const unsigned short* qh = q_ws + (size_t)bh * S_LEN * DH;
    const unsigned short* kh = k_ws + (size_t)bh * S_LEN * DH;
    const unsigned short* vh = vt_ws + (size_t)bh * DH * S_LEN;
    const unsigned* mrA = mbits + (size_t)(b * S_LEN + qA) * (S_LEN / 32);
    const unsigned* mrB = mbits + (size_t)(b * S_LEN + qB) * (S_LEN / 32);

    // Q fragments (B operand of K*Q^T): Q[q][dh = c*32 + lg*8 + j].
    bf16x8 aqA[2], aqB[2];
#pragma unroll
    for (int c = 0; c < 2; c++) {
        aqA[c] = *(const bf16x8*)(&qh[(size_t)qA * DH + c * 32 + lg * 8]);
        aqB[c] = *(const bf16x8*)(&qh[(size_t)qB * DH + c * 32 + lg * 8]);
    }

    bf16x8 ones;
#pragma unroll
    for (int j = 0; j < 8; j++) ones[j] = (__bf16)1.0f;

    f32x4 accA[4], accB[4], accRA, accRB;
#pragma unroll
    for (int di = 0; di < 4; di++) {
        accA[di] = f32x4{0.f, 0.f, 0.f, 0.f};
        accB[di] = f32x4{0.f, 0.f, 0.f, 0.f};
    }
    accRA = f32x4{0.f, 0.f, 0.f, 0.f};
    accRB = f32x4{0.f, 0.f, 0.f, 0.f};

    // Prologue: tile 0 -> Ks[0]/Vs[0]; tile 1 -> staging regs.
    uint4 kreg0, kreg1, vreg0, vreg1;
    kreg0 = *(const uint4*)(&kh[(size_t)(srow)      * DH + sseg * 8]);
    kreg1 = *(const uint4*)(&kh[(size_t)(srow + 32) * DH + sseg * 8]);
    vreg0 = *(const uint4*)(&vh[(size_t)(srow)      * S_LEN + sseg * 8]);
    vreg1 = *(const uint4*)(&vh[(size_t)(srow + 32) * S_LEN + sseg * 8]);
    *(uint4*)(&Ks[0][(srow)      * 72 + sseg * 8]) = kreg0;
    *(uint4*)(&Ks[0][(srow + 32) * 72 + sseg * 8]) = kreg1;
    *(uint4*)(&Vs[0][(srow)      * 72 + sseg * 8]) = vreg0;
    *(uint4*)(&Vs[0][(srow + 32) * 72 + sseg * 8]) = vreg1;
    kreg0 = *(const uint4*)(&kh[(size_t)(64 + srow)      * DH + sseg * 8]);
    kreg1 = *(const uint4*)(&kh[(size_t)(64 + srow + 32) * DH + sseg * 8]);
    vreg0 = *(const uint4*)(&vh[(size_t)(srow)      * S_LEN + 64 + sseg * 8]);
    vreg1 = *(const uint4*)(&vh[(size_t)(srow + 32) * S_LEN + 64 + sseg * 8]);
    __syncthreads();

    for (int it = 0; it < 32; it++) {
        const int cur = it & 1;
        const unsigned short* Kc = &Ks[cur][0];
        const unsigned short* Vc = &Vs[cur][0];
        if (it < 31) {
            unsigned short* Kn = &Ks[cur ^ 1][0];
            unsigned short* Vn = &Vs[cur ^ 1][0];
            *(uint4*)(&Kn[(srow)      * 72 + sseg * 8]) = kreg0;
            *(uint4*)(&Kn[(srow + 32) * 72 + sseg * 8]) = kreg1;
            *(uint4*)(&Vn[(srow)      * 72 + sseg * 8]) = vreg0;
            *(uint4*)(&Vn[(srow + 32) * 72 + sseg * 8]) = vreg1;
        }
        if (it < 30) {
            const int kn = (it + 2) * 64;
            kreg0 = *(const uint4*)(&kh[(size_t)(kn + srow)      * DH + sseg * 8]);
            kreg1 = *(const uint4*)(&kh[(size_t)(kn + srow + 32) * DH + sseg * 8]);
            vreg0 = *(const uint4*)(&vh[(size_t)(srow)      * S_LEN + kn + sseg * 8]);
            vreg1 = *(const uint4*)(&vh[(size_t)(srow + 32) * S_LEN + kn + sseg * 8]);
        }

        const uint2 mwA = *(const uint2*)(&mrA[it * 2]);
        const uint2 mwB = *(const uint2*)(&mrB[it * 2]);

        // S^T tiles: D[row=kv_loc=lg*4+r][col=q=lr], kv = it*64+ni*16+lg*4+r.
        f32x4 sA[4], sB[4];
        __builtin_amdgcn_s_setprio(1);
#pragma unroll
        for (int ni = 0; ni < 4; ni++) {
            bf16x8 ak0 = *(const bf16x8*)(&Kc[(ni * 16 + lr) * 72 + lg * 8]);
            bf16x8 ak1 = *(const bf16x8*)(&Kc[(ni * 16 + lr) * 72 + 32 + lg * 8]);
            f32x4 tA = __builtin_amdgcn_mfma_f32_16x16x32_bf16(ak0, aqA[0], f32x4{0.f,0.f,0.f,0.f}, 0,0,0);
            tA = __builtin_amdgcn_mfma_f32_16x16x32_bf16(ak1, aqA[1], tA, 0,0,0);
            f32x4 tB = __builtin_amdgcn_mfma_f32_16x16x32_bf16(ak0, aqB[0], f32x4{0.f,0.f,0.f,0.f}, 0,0,0);
            tB = __builtin_amdgcn_mfma_f32_16x16x32_bf16(ak1, aqB[1], tB, 0,0,0);
            sA[ni] = tA; sB[ni] = tB;
        }
        __builtin_amdgcn_s_setprio(0);

        // Softmax numerator: p = masked ? 0 : exp2(s)  (s pre-scaled in Q).
#pragma unroll
        for (int ni = 0; ni < 4; ni++) {
            unsigned wA = (ni & 2) ? mwA.y : mwA.x;
            unsigned wB = (ni & 2) ? mwB.y : mwB.x;
            unsigned nibA = wA >> ((ni & 1) * 16 + lg * 4);
            unsigned nibB = wB >> ((ni & 1) * 16 + lg * 4);
#pragma unroll
            for (int r = 0; r < 4; r++) {
                float pA = exp2_hw(sA[ni][r]);
                float pB = exp2_hw(sB[ni][r]);
                sA[ni][r] = (nibA & (1u << r)) ? 0.f : pA;
                sB[ni][r] = (nibB & (1u << r)) ? 0.f : pB;
            }
        }

        // In-register P^T: lane (lr,lg) holds P[q=lr][kv=16ni+4lg+r].
        // Pack r-pairs then 2-stage permlane butterfly -> lane (lr,g) holds
        // P[q=lr][kv = 32c + 8g + j], j=0..7 (verified in R14).
        unsigned wpA[8], wpB[8];
#pragma unroll
        for (int ni = 0; ni < 4; ni++) {
            wpA[ni*2]   = cvtpk_bf16(sA[ni][0], sA[ni][1]);
            wpA[ni*2+1] = cvtpk_bf16(sA[ni][2], sA[ni][3]);
            wpB[ni*2]   = cvtpk_bf16(sB[ni][0], sB[ni][1]);
            wpB[ni*2+1] = cvtpk_bf16(sB[ni][2], sB[ni][3]);
        }
#pragma unroll
        for (int c = 0; c < 2; c++) {
            pl32swap(wpA[c*4 + 0], wpA[c*4 + 2]);
            pl32swap(wpA[c*4 + 1], wpA[c*4 + 3]);
            pl16swap(wpA[c*4 + 0], wpA[c*4 + 2]);
            pl16swap(wpA[c*4 + 1], wpA[c*4 + 3]);
            pl32swap(wpB[c*4 + 0], wpB[c*4 + 2]);
            pl32swap(wpB[c*4 + 1], wpB[c*4 + 3]);
            pl16swap(wpB[c*4 + 0], wpB[c*4 + 2]);
            pl16swap(wpB[c*4 + 1], wpB[c*4 + 3]);
        }
        bf16x8 bpA0, bpA1, bpB0, bpB1;
        __builtin_memcpy(&bpA0, &wpA[0], 16);
        __builtin_memcpy(&bpA1, &wpA[4], 16);
        __builtin_memcpy(&bpB0, &wpB[0], 16);
        __builtin_memcpy(&bpB1, &wpB[4], 16);

        // O^T += V^T * P^T; row sums on the matrix pipe.
        __builtin_amdgcn_s_setprio(1);
#pragma unroll
        for (int di = 0; di < 4; di++) {
            bf16x8 av0 = *(const bf16x8*)(&Vc[(di * 16 + lr) * 72 + lg * 8]);
            bf16x8 av1 = *(const bf16x8*)(&Vc[(di * 16 + lr) * 72 + 32 + lg * 8]);
            accA[di] = __builtin_amdgcn_mfma_f32_16x16x32_bf16(av0, bpA0, accA[di], 0, 0, 0);
            accA[di] = __builtin_amdgcn_mfma_f32_16x16x32_bf16(av1, bpA1, accA[di], 0, 0, 0);
            accB[di] = __builtin_amdgcn_mfma_f32_16x16x32_bf16(av0, bpB0, accB[di], 0, 0, 0);
            accB[di] = __builtin_amdgcn_mfma_f32_16x16x32_bf16(av1, bpB1, accB[di], 0, 0, 0);
        }
        accRA = __builtin_amdgcn_mfma_f32_16x16x32_bf16(ones, bpA0, accRA, 0, 0, 0);
        accRA = __builtin_amdgcn_mfma_f32_16x16x32_bf16(ones, bpA1, accRA, 0, 0, 0);
        accRB = __builtin_amdgcn_mfma_f32_16x16x32_bf16(ones, bpB0, accRB, 0, 0, 0);
        accRB = __builtin_amdgcn_mfma_f32_16x16x32_bf16(ones, bpB1, accRB, 0, 0, 0);
        __builtin_amdgcn_s_setprio(0);

        __syncthreads();
    }

    const float invA = 1.0f / fmaxf(accRA[0], 1e-37f);
    const float invB = 1.0f / fmaxf(accRB[0], 1e-37f);

    unsigned short* crowA = &ctx[((size_t)(b * S_LEN + qA)) * DM + h * DH];
    unsigned short* crowB = &ctx[((size_t)(b * S_LEN + qB)) * DM + h * DH];
#pragma unroll
    for (int di = 0; di < 4; di++) {
        bf16x4 oA, oB;
#pragma unroll
        for (int r = 0; r < 4; r++) {
            oA[r] = (__bf16)(accA[di][r] * invA);
            oB[r] = (__bf16)(accB[di][r] * invB);
        }
        *(bf16x4*)(&crowA[di * 16 + lg * 4]) = oA;
        *(bf16x4*)(&crowB[di * 16 + lg * 4]) = oB;
    }
}

extern "C" void kernel_launch(void* const* d_in, const int* in_sizes, int n_in,
                              void* d_out, int out_size, void* d_ws, size_t ws_size,
                              hipStream_t stream)
{
    (void)in_sizes; (void)n_in; (void)out_size; (void)ws_size;
    const float* Q  = (const float*)d_in[0];
    const float* K  = (const float*)d_in[1];
    const float* V  = (const float*)d_in[2];
    const int*   Mk = (const int*)d_in[3];
    const float* Wq = (const float*)d_in[4];
    const float* bq = (const float*)d_in[5];
    const float* Wk = (const float*)d_in[6];
    const float* bk = (const float*)d_in[7];
    const float* Wv = (const float*)d_in[8];
    const float* bv = (const float*)d_in[9];
    const float* Wo = (const float*)d_in[10];
    const float* bo = (const float*)d_in[11];

    const int NX = MROWS * DM;   // 4194304
    const int NW = DM * DM;      // 1048576

    unsigned short* q_ws  = (unsigned short*)d_ws;
    unsigned short* k_ws  = q_ws + (size_t)NX;
    unsigned short* vt_ws = k_ws + (size_t)NX;
    unsigned short* ctx   = vt_ws + (size_t)NX;
    unsigned*       mbits = (unsigned*)(ctx + (size_t)NX);
    unsigned short* Wbq   = (unsigned short*)(mbits + (size_t)MROWS * (S_LEN / 32));
    unsigned short* Wbk   = Wbq + (size_t)NW;
    unsigned short* Wbv   = Wbk + (size_t)NW;
    unsigned short* Wbo   = Wbv + (size_t)NW;
    unsigned short* Xbq   = Wbo + (size_t)NW;
    unsigned short* Xbk   = Xbq + (size_t)NX;
    unsigned short* Xbv   = Xbk + (size_t)NX;
    float* out = (float*)d_out;

    dim3 blk(256);
    prep<<<dim3(9216), blk, 0, stream>>>(Mk, mbits, Q, Xbq, K, Xbk, V, Xbv,
                                         Wq, Wbq, Wk, Wbk, Wv, Wbv, Wo, Wbo);

    gemm128<<<dim3(8, 32, 3), blk, 0, stream>>>(Xbq, Xbk, Xbv, Wbq, Wbk, Wbv,
                                                bq, bk, bv, q_ws, k_ws, vt_ws);

    attn<<<dim3(512), blk, 0, stream>>>(q_ws, k_ws, vt_ws, mbits, ctx);

    gemm_out<<<dim3(16, 32), blk, 0, stream>>>(ctx, Wbo, bo, out);
}